// Round 2
// baseline (2972.745 us; speedup 1.0000x reference)
//
#include <hip/hip_runtime.h>

constexpr int IN   = 256;
constexpr int H    = 256;
constexpr int STR  = 60;
constexpr int NLOC = 8;

// ---------------- degree histogram ----------------
__global__ void k_deg(const int* __restrict__ row, int* __restrict__ deg, int E) {
  int i = blockIdx.x*blockDim.x + threadIdx.x;
  int stride = gridDim.x*blockDim.x;
  for (; i < E; i += stride) atomicAdd(&deg[row[i]], 1);
}

// ---------------- pos_embedding: pe[i,j] = cat(pos_emb,lap_pe)[i,:] @ W_pos[:,j] ----------------
__global__ void k_pe(const float* __restrict__ pos_emb, const float* __restrict__ lap_pe,
                     const float* __restrict__ W, const float* __restrict__ b,
                     float* __restrict__ pe, int n) {
  int i = blockIdx.x*blockDim.x + threadIdx.x;
  if (i >= n) return;
  float acc[NLOC];
  #pragma unroll
  for (int j = 0; j < NLOC; ++j) acc[j] = b[j];
  const float* pr = pos_emb + (size_t)i*STR;
  for (int k = 0; k < STR; ++k) {
    float v = pr[k];
    #pragma unroll
    for (int j = 0; j < NLOC; ++j) acc[j] += v*W[k*NLOC + j];
  }
  const float* lr = lap_pe + (size_t)i*(STR-1);
  for (int k = 0; k < STR-1; ++k) {
    float v = lr[k];
    #pragma unroll
    for (int j = 0; j < NLOC; ++j) acc[j] += v*W[(STR+k)*NLOC + j];
  }
  float* po = pe + (size_t)i*NLOC;
  #pragma unroll
  for (int j = 0; j < NLOC; ++j) po[j] = acc[j];
}

// ---------------- single-block exclusive scan + norm ----------------
__global__ void k_scan_all(const int* __restrict__ deg, int* __restrict__ rp,
                           float* __restrict__ norm, int n, int E) {
  __shared__ int sh[1024];
  __shared__ int carry_s;
  int t = threadIdx.x;
  if (t == 0) carry_s = 0;
  __syncthreads();
  for (int base = 0; base < n; base += 1024) {
    int i = base + t;
    int v = (i < n) ? deg[i] : 0;
    sh[t] = v;
    __syncthreads();
    for (int off = 1; off < 1024; off <<= 1) {
      int val = (t >= off) ? sh[t - off] : 0;
      __syncthreads();
      sh[t] += val;
      __syncthreads();
    }
    int carry = carry_s;                 // stable: updated only after next barrier
    if (i < n) {
      rp[i] = carry + sh[t] - v;         // exclusive prefix
      norm[i] = rsqrtf(1.0f + (float)v);
    }
    __syncthreads();
    if (t == 1023) carry_s += sh[1023];
    __syncthreads();
  }
  if (t == 0) rp[n] = E;
}

// ---------------- scatter cols into CSR ----------------
__global__ void k_scatter(const int* __restrict__ row, const int* __restrict__ col,
                          const int* __restrict__ rp, int* __restrict__ cnt,
                          int* __restrict__ colbuf, int E) {
  int i = blockIdx.x*blockDim.x + threadIdx.x;
  int stride = gridDim.x*blockDim.x;
  for (; i < E; i += stride) {
    int r = row[i];
    int p = rp[r] + atomicAdd(&cnt[r], 1);
    colbuf[p] = col[i];
  }
}

// ---------------- xemb: h[i,j] = [x|pe][i,:] @ W[:,j] + b[j]  (one block per row) ----------------
__global__ __launch_bounds__(256) void k_xemb(
    const float* __restrict__ x, const float* __restrict__ pe,
    const float* __restrict__ W, const float* __restrict__ bvec,
    float* __restrict__ h, int n) {
  __shared__ float xs[IN + NLOC];
  int i = blockIdx.x;
  int j = threadIdx.x;
  if (i >= n) return;
  xs[j] = x[(size_t)i*IN + j];
  if (j < NLOC) xs[IN + j] = pe[(size_t)i*NLOC + j];
  __syncthreads();
  float acc = bvec[j];
  #pragma unroll 4
  for (int k = 0; k < IN; ++k) acc += xs[k]*W[(size_t)k*H + j];
  #pragma unroll
  for (int k = 0; k < NLOC; ++k) acc += xs[IN+k]*W[(size_t)(IN+k)*H + j];
  h[(size_t)i*H + j] = acc;
}

// ---------------- hs = norm * h (elementwise) ----------------
__global__ void k_scale(const float* __restrict__ h, const float* __restrict__ norm,
                        float* __restrict__ hs, int n) {
  size_t total4 = (size_t)n * (H/4);
  size_t i = (size_t)blockIdx.x*blockDim.x + threadIdx.x;
  size_t stride = (size_t)gridDim.x*blockDim.x;
  for (; i < total4; i += stride) {
    float4 v = ((const float4*)h)[i];
    float nr = norm[(i*4) >> 8];
    ((float4*)hs)[i] = make_float4(nr*v.x, nr*v.y, nr*v.z, nr*v.w);
  }
}

// ---------------- layer: u = norm*(A@hs + hs); out (+)= jk*u; hnext = u ----------------
__global__ __launch_bounds__(256) void k_layer(
    const float* __restrict__ hs, const int* __restrict__ rp,
    const int* __restrict__ colbuf, const float* __restrict__ norm,
    const float* __restrict__ jkp, int l, int first,
    float* __restrict__ out, float* __restrict__ hnext, int n) {
  int wid = (int)(((size_t)blockIdx.x*blockDim.x + threadIdx.x) >> 6);
  if (wid >= n) return;
  int lane = threadIdx.x & 63;
  int start = rp[wid], end = rp[wid+1];
  const float* base = hs + (size_t)lane*4;
  float4 acc = make_float4(0.f,0.f,0.f,0.f);
  int j = start;
  for (; j + 2 <= end; j += 2) {
    int c0 = colbuf[j];
    int c1 = colbuf[j+1];
    float4 v0 = *(const float4*)(base + (size_t)c0*H);
    float4 v1 = *(const float4*)(base + (size_t)c1*H);
    acc.x += v0.x + v1.x;
    acc.y += v0.y + v1.y;
    acc.z += v0.z + v1.z;
    acc.w += v0.w + v1.w;
  }
  if (j < end) {
    int c0 = colbuf[j];
    float4 v0 = *(const float4*)(base + (size_t)c0*H);
    acc.x += v0.x; acc.y += v0.y; acc.z += v0.z; acc.w += v0.w;
  }
  float nr = norm[wid];
  float jk = jkp[l];
  float4 hv = *(const float4*)(hs + (size_t)wid*H + lane*4);
  float4 u = make_float4(nr*(acc.x+hv.x), nr*(acc.y+hv.y),
                         nr*(acc.z+hv.z), nr*(acc.w+hv.w));
  float* op = out + (size_t)wid*H + lane*4;
  if (first) {
    *(float4*)op = make_float4(jk*u.x, jk*u.y, jk*u.z, jk*u.w);
  } else {
    float4 o = *(const float4*)op;
    o.x += jk*u.x; o.y += jk*u.y; o.z += jk*u.z; o.w += jk*u.w;
    *(float4*)op = o;
  }
  *(float4*)(hnext + (size_t)wid*H + lane*4) = u;
}

extern "C" void kernel_launch(void* const* d_in, const int* in_sizes, int n_in,
                              void* d_out, int out_size, void* d_ws, size_t ws_size,
                              hipStream_t stream) {
  const float* x       = (const float*)d_in[0];
  const float* pos_emb = (const float*)d_in[1];
  const float* lap_pe  = (const float*)d_in[2];
  const float* W_pos   = (const float*)d_in[3];
  const float* b_pos   = (const float*)d_in[4];
  const float* W_xemb  = (const float*)d_in[5];
  const float* b_xemb  = (const float*)d_in[6];
  const float* jkp     = (const float*)d_in[7];
  const int*   row     = (const int*)d_in[8];
  const int*   col     = (const int*)d_in[9];
  int N = in_sizes[0] / IN;
  int E = in_sizes[8];
  float* out = (float*)d_out;

  char* p = (char*)d_ws;
  auto alloc = [&](size_t bytes) {
    char* r = p; p += (bytes + 255) & ~(size_t)255; return r;
  };
  float* hA     = (float*)alloc((size_t)N*H*4);   // h (current layer input)
  float* hB     = (float*)alloc((size_t)N*H*4);   // hs (scaled)
  int*   colbuf = (int*)  alloc((size_t)E*4);
  float* pe     = (float*)alloc((size_t)N*NLOC*4);
  int*   deg    = (int*)  alloc((size_t)N*4);
  int*   cnt    = (int*)  alloc((size_t)N*4);
  int*   rp     = (int*)  alloc((size_t)(N+1)*4);
  float* norm   = (float*)alloc((size_t)N*4);

  hipMemsetAsync(deg, 0, (size_t)N*4, stream);
  hipMemsetAsync(cnt, 0, (size_t)N*4, stream);

  k_deg<<<2048, 256, 0, stream>>>(row, deg, E);
  k_pe<<<(N+255)/256, 256, 0, stream>>>(pos_emb, lap_pe, W_pos, b_pos, pe, N);
  k_scan_all<<<1, 1024, 0, stream>>>(deg, rp, norm, N, E);
  k_scatter<<<2048, 256, 0, stream>>>(row, col, rp, cnt, colbuf, E);
  k_xemb<<<N, 256, 0, stream>>>(x, pe, W_xemb, b_xemb, hA, N);

  int lg = (int)(((size_t)N*64 + 255)/256);   // one wave per row
  for (int l = 0; l < 3; ++l) {
    k_scale<<<2048, 256, 0, stream>>>(hA, norm, hB, N);
    k_layer<<<lg, 256, 0, stream>>>(hB, rp, colbuf, norm, jkp, l, (l==0)?1:0,
                                    out, hA, N);
  }
}

// Round 3
// 1425.276 us; speedup vs baseline: 2.0857x; 2.0857x over previous
//
#include <hip/hip_runtime.h>

constexpr int IN   = 256;
constexpr int H    = 256;
constexpr int STR  = 60;
constexpr int NLOC = 8;

__device__ __forceinline__ float bflo(unsigned u) { return __uint_as_float(u << 16); }
__device__ __forceinline__ float bfhi(unsigned u) { return __uint_as_float(u & 0xFFFF0000u); }
__device__ __forceinline__ unsigned short f2bf(float f) {
  unsigned u = __float_as_uint(f);
  u += 0x7FFF + ((u >> 16) & 1);          // round-to-nearest-even
  return (unsigned short)(u >> 16);
}

// ---------------- degree histogram ----------------
__global__ void k_deg(const int* __restrict__ row, int* __restrict__ deg, int E) {
  int i = blockIdx.x*blockDim.x + threadIdx.x;
  int stride = gridDim.x*blockDim.x;
  for (; i < E; i += stride) atomicAdd(&deg[row[i]], 1);
}

// ---------------- pos_embedding ----------------
__global__ void k_pe(const float* __restrict__ pos_emb, const float* __restrict__ lap_pe,
                     const float* __restrict__ W, const float* __restrict__ b,
                     float* __restrict__ pe, int n) {
  int i = blockIdx.x*blockDim.x + threadIdx.x;
  if (i >= n) return;
  float acc[NLOC];
  #pragma unroll
  for (int j = 0; j < NLOC; ++j) acc[j] = b[j];
  const float* pr = pos_emb + (size_t)i*STR;
  for (int k = 0; k < STR; ++k) {
    float v = pr[k];
    #pragma unroll
    for (int j = 0; j < NLOC; ++j) acc[j] += v*W[k*NLOC + j];
  }
  const float* lr = lap_pe + (size_t)i*(STR-1);
  for (int k = 0; k < STR-1; ++k) {
    float v = lr[k];
    #pragma unroll
    for (int j = 0; j < NLOC; ++j) acc[j] += v*W[(STR+k)*NLOC + j];
  }
  float* po = pe + (size_t)i*NLOC;
  #pragma unroll
  for (int j = 0; j < NLOC; ++j) po[j] = acc[j];
}

// ---------------- single-block exclusive scan + norm (proven correct) ----------------
__global__ void k_scan_all(const int* __restrict__ deg, int* __restrict__ rp,
                           float* __restrict__ norm, int n, int E) {
  __shared__ int sh[1024];
  __shared__ int carry_s;
  int t = threadIdx.x;
  if (t == 0) carry_s = 0;
  __syncthreads();
  for (int base = 0; base < n; base += 1024) {
    int i = base + t;
    int v = (i < n) ? deg[i] : 0;
    sh[t] = v;
    __syncthreads();
    for (int off = 1; off < 1024; off <<= 1) {
      int val = (t >= off) ? sh[t - off] : 0;
      __syncthreads();
      sh[t] += val;
      __syncthreads();
    }
    int carry = carry_s;
    if (i < n) {
      rp[i] = carry + sh[t] - v;
      norm[i] = rsqrtf(1.0f + (float)v);
    }
    __syncthreads();
    if (t == 1023) carry_s += sh[1023];
    __syncthreads();
  }
  if (t == 0) rp[n] = E;
}

// ---------------- scatter cols into CSR ----------------
__global__ void k_scatter(const int* __restrict__ row, const int* __restrict__ col,
                          const int* __restrict__ rp, int* __restrict__ cnt,
                          int* __restrict__ colbuf, int E) {
  int i = blockIdx.x*blockDim.x + threadIdx.x;
  int stride = gridDim.x*blockDim.x;
  for (; i < E; i += stride) {
    int r = row[i];
    int p = rp[r] + atomicAdd(&cnt[r], 1);
    colbuf[p] = col[i];
  }
}

// ---------------- xemb tiled GEMM: hbf = bf16( norm * ([x|pe] @ W + b) ) ----------------
// grid (ceil(n/64), 4), block 256. BM=BN=64, BK=8, 4x4 micro-tile.
// K = 264 = 33 tiles of 8; tile 32 (k0=256) maps exactly onto pe rows.
__global__ __launch_bounds__(256) void k_xemb(
    const float* __restrict__ x, const float* __restrict__ pe,
    const float* __restrict__ W, const float* __restrict__ bvec,
    const float* __restrict__ norm, unsigned short* __restrict__ hbf, int n) {
  __shared__ float As[8][64];    // [k][m]
  __shared__ float Bs[8][64];    // [k][n]
  int t  = threadIdx.x;
  int i0 = blockIdx.x*64;
  int n0 = blockIdx.y*64;
  // A staging: 64 rows x 8 k, float2 per thread
  int am = t >> 2;               // 0..63
  int ak = (t & 3) * 2;          // 0,2,4,6
  int arow = i0 + am; if (arow >= n) arow = n - 1;
  // B staging: 8 k x 64 n, float2 per thread
  int bk = t >> 5;               // 0..7
  int bn = (t & 31) * 2;         // 0..62
  int tx = t & 15, ty = t >> 4;
  float acc[4][4] = {};
  for (int k0 = 0; k0 < 264; k0 += 8) {
    float2 av;
    if (k0 < 256) av = *(const float2*)&x[(size_t)arow*IN + k0 + ak];
    else          av = *(const float2*)&pe[(size_t)arow*NLOC + ak];
    float2 bv = *(const float2*)&W[(size_t)(k0 + bk)*H + n0 + bn];
    __syncthreads();
    As[ak][am] = av.x; As[ak+1][am] = av.y;
    Bs[bk][bn] = bv.x; Bs[bk][bn+1] = bv.y;
    __syncthreads();
    #pragma unroll
    for (int k = 0; k < 8; ++k) {
      float4 a = *(const float4*)&As[k][ty*4];
      float4 b = *(const float4*)&Bs[k][tx*4];
      float aa[4] = {a.x,a.y,a.z,a.w};
      float bb[4] = {b.x,b.y,b.z,b.w};
      #pragma unroll
      for (int ii = 0; ii < 4; ++ii)
        #pragma unroll
        for (int jj = 0; jj < 4; ++jj) acc[ii][jj] += aa[ii]*bb[jj];
    }
  }
  float4 bias = *(const float4*)&bvec[n0 + tx*4];
  float bb4[4] = {bias.x, bias.y, bias.z, bias.w};
  #pragma unroll
  for (int ii = 0; ii < 4; ++ii) {
    int i = i0 + ty*4 + ii;
    if (i < n) {
      float nr = norm[i];
      unsigned short s0 = f2bf(nr*(acc[ii][0] + bb4[0]));
      unsigned short s1 = f2bf(nr*(acc[ii][1] + bb4[1]));
      unsigned short s2 = f2bf(nr*(acc[ii][2] + bb4[2]));
      unsigned short s3 = f2bf(nr*(acc[ii][3] + bb4[3]));
      uint2 pk;
      pk.x = (unsigned)s0 | ((unsigned)s1 << 16);
      pk.y = (unsigned)s2 | ((unsigned)s3 << 16);
      *(uint2*)&hbf[(size_t)i*H + n0 + tx*4] = pk;
    }
  }
}

// ---------------- layer: u = norm*(A@hs + hs); out (+)= jk*u; hbf_next = bf16(norm*u) ----------------
// hs is the bf16 state. One wave per row; lane owns 4 columns (8 bytes bf16).
__global__ __launch_bounds__(256) void k_layer(
    const unsigned short* __restrict__ hbf, const int* __restrict__ rp,
    const int* __restrict__ colbuf, const float* __restrict__ norm,
    const float* __restrict__ jkp, int l, int first, int last,
    float* __restrict__ out, unsigned short* __restrict__ hbf_next, int n) {
  int wid = (int)(((size_t)blockIdx.x*blockDim.x + threadIdx.x) >> 6);
  if (wid >= n) return;
  int lane = threadIdx.x & 63;
  const uint2* gb = (const uint2*)hbf + lane;   // row stride = 64 uint2
  int start = rp[wid], end = rp[wid+1];
  float4 acc = make_float4(0.f,0.f,0.f,0.f);
  int j = start;
  for (; j + 4 <= end; j += 4) {
    int c0 = colbuf[j], c1 = colbuf[j+1], c2 = colbuf[j+2], c3 = colbuf[j+3];
    uint2 v0 = gb[(size_t)c0*64];
    uint2 v1 = gb[(size_t)c1*64];
    uint2 v2 = gb[(size_t)c2*64];
    uint2 v3 = gb[(size_t)c3*64];
    acc.x += (bflo(v0.x)+bflo(v1.x)) + (bflo(v2.x)+bflo(v3.x));
    acc.y += (bfhi(v0.x)+bfhi(v1.x)) + (bfhi(v2.x)+bfhi(v3.x));
    acc.z += (bflo(v0.y)+bflo(v1.y)) + (bflo(v2.y)+bflo(v3.y));
    acc.w += (bfhi(v0.y)+bfhi(v1.y)) + (bfhi(v2.y)+bfhi(v3.y));
  }
  for (; j < end; ++j) {
    int c0 = colbuf[j];
    uint2 v0 = gb[(size_t)c0*64];
    acc.x += bflo(v0.x); acc.y += bfhi(v0.x);
    acc.z += bflo(v0.y); acc.w += bfhi(v0.y);
  }
  // self term
  uint2 sv = gb[(size_t)wid*64];
  acc.x += bflo(sv.x); acc.y += bfhi(sv.x);
  acc.z += bflo(sv.y); acc.w += bfhi(sv.y);
  float nr = norm[wid];
  float jk = jkp[l];
  float4 u = make_float4(nr*acc.x, nr*acc.y, nr*acc.z, nr*acc.w);
  float* op = out + (size_t)wid*H + lane*4;
  if (first) {
    *(float4*)op = make_float4(jk*u.x, jk*u.y, jk*u.z, jk*u.w);
  } else {
    float4 o = *(const float4*)op;
    o.x += jk*u.x; o.y += jk*u.y; o.z += jk*u.z; o.w += jk*u.w;
    *(float4*)op = o;
  }
  if (!last) {
    unsigned short s0 = f2bf(nr*u.x);
    unsigned short s1 = f2bf(nr*u.y);
    unsigned short s2 = f2bf(nr*u.z);
    unsigned short s3 = f2bf(nr*u.w);
    uint2 pk;
    pk.x = (unsigned)s0 | ((unsigned)s1 << 16);
    pk.y = (unsigned)s2 | ((unsigned)s3 << 16);
    *(uint2*)&hbf_next[(size_t)wid*H + lane*4] = pk;
  }
}

extern "C" void kernel_launch(void* const* d_in, const int* in_sizes, int n_in,
                              void* d_out, int out_size, void* d_ws, size_t ws_size,
                              hipStream_t stream) {
  const float* x       = (const float*)d_in[0];
  const float* pos_emb = (const float*)d_in[1];
  const float* lap_pe  = (const float*)d_in[2];
  const float* W_pos   = (const float*)d_in[3];
  const float* b_pos   = (const float*)d_in[4];
  const float* W_xemb  = (const float*)d_in[5];
  const float* b_xemb  = (const float*)d_in[6];
  const float* jkp     = (const float*)d_in[7];
  const int*   row     = (const int*)d_in[8];
  const int*   col     = (const int*)d_in[9];
  int N = in_sizes[0] / IN;
  int E = in_sizes[8];
  float* out = (float*)d_out;

  char* p = (char*)d_ws;
  auto alloc = [&](size_t bytes) {
    char* r = p; p += (bytes + 255) & ~(size_t)255; return r;
  };
  unsigned short* bfA = (unsigned short*)alloc((size_t)N*H*2);  // 51.2 MB
  unsigned short* bfB = (unsigned short*)alloc((size_t)N*H*2);  // 51.2 MB
  int*   colbuf = (int*)  alloc((size_t)E*4);                   // 12.8 MB
  float* pe     = (float*)alloc((size_t)N*NLOC*4);
  int*   deg    = (int*)  alloc((size_t)N*4);
  int*   cnt    = (int*)  alloc((size_t)N*4);
  int*   rp     = (int*)  alloc((size_t)(N+1)*4);
  float* norm   = (float*)alloc((size_t)N*4);

  hipMemsetAsync(deg, 0, (size_t)N*4, stream);
  hipMemsetAsync(cnt, 0, (size_t)N*4, stream);

  k_deg<<<2048, 256, 0, stream>>>(row, deg, E);
  k_pe<<<(N+255)/256, 256, 0, stream>>>(pos_emb, lap_pe, W_pos, b_pos, pe, N);
  k_scan_all<<<1, 1024, 0, stream>>>(deg, rp, norm, N, E);
  k_scatter<<<2048, 256, 0, stream>>>(row, col, rp, cnt, colbuf, E);

  dim3 gg((N+63)/64, 4);
  k_xemb<<<gg, 256, 0, stream>>>(x, pe, W_xemb, b_xemb, norm, bfA, N);

  int lg = (int)(((size_t)N*64 + 255)/256);   // one wave per row
  k_layer<<<lg, 256, 0, stream>>>(bfA, rp, colbuf, norm, jkp, 0, 1, 0, out, bfB, N);
  k_layer<<<lg, 256, 0, stream>>>(bfB, rp, colbuf, norm, jkp, 1, 0, 0, out, bfA, N);
  k_layer<<<lg, 256, 0, stream>>>(bfA, rp, colbuf, norm, jkp, 2, 0, 1, out, bfB, N);
}

// Round 4
// 1253.908 us; speedup vs baseline: 2.3708x; 1.1367x over previous
//
#include <hip/hip_runtime.h>

constexpr int IN   = 256;
constexpr int H    = 256;
constexpr int STR  = 60;
constexpr int NLOC = 8;

__device__ __forceinline__ float bflo(unsigned u) { return __uint_as_float(u << 16); }
__device__ __forceinline__ float bfhi(unsigned u) { return __uint_as_float(u & 0xFFFF0000u); }
__device__ __forceinline__ unsigned short f2bf(float f) {
  unsigned u = __float_as_uint(f);
  u += 0x7FFF + ((u >> 16) & 1);          // round-to-nearest-even
  return (unsigned short)(u >> 16);
}

// ---------------- degree histogram ----------------
__global__ void k_deg(const int* __restrict__ row, int* __restrict__ deg, int E) {
  int i = blockIdx.x*blockDim.x + threadIdx.x;
  int stride = gridDim.x*blockDim.x;
  for (; i < E; i += stride) atomicAdd(&deg[row[i]], 1);
}

// ---------------- pos_embedding ----------------
__global__ void k_pe(const float* __restrict__ pos_emb, const float* __restrict__ lap_pe,
                     const float* __restrict__ W, const float* __restrict__ b,
                     float* __restrict__ pe, int n) {
  int i = blockIdx.x*blockDim.x + threadIdx.x;
  if (i >= n) return;
  float acc[NLOC];
  #pragma unroll
  for (int j = 0; j < NLOC; ++j) acc[j] = b[j];
  const float* pr = pos_emb + (size_t)i*STR;
  for (int k = 0; k < STR; ++k) {
    float v = pr[k];
    #pragma unroll
    for (int j = 0; j < NLOC; ++j) acc[j] += v*W[k*NLOC + j];
  }
  const float* lr = lap_pe + (size_t)i*(STR-1);
  for (int k = 0; k < STR-1; ++k) {
    float v = lr[k];
    #pragma unroll
    for (int j = 0; j < NLOC; ++j) acc[j] += v*W[(STR+k)*NLOC + j];
  }
  float* po = pe + (size_t)i*NLOC;
  #pragma unroll
  for (int j = 0; j < NLOC; ++j) po[j] = acc[j];
}

// ---------------- multi-block exclusive scan (3 kernels) ----------------
__global__ void k_scan1(const int* __restrict__ deg, int* __restrict__ rp,
                        int* __restrict__ partials, int n) {
  __shared__ int sh[256];
  int b = blockIdx.x;
  int t = threadIdx.x;
  int base = b*1024 + t*4;
  int v0 = base+0 < n ? deg[base+0] : 0;
  int v1 = base+1 < n ? deg[base+1] : 0;
  int v2 = base+2 < n ? deg[base+2] : 0;
  int v3 = base+3 < n ? deg[base+3] : 0;
  int ts = v0+v1+v2+v3;
  sh[t] = ts;
  __syncthreads();
  for (int off = 1; off < 256; off <<= 1) {
    int val = (t >= off) ? sh[t - off] : 0;
    __syncthreads();
    sh[t] += val;
    __syncthreads();
  }
  int ex = sh[t] - ts;                   // exclusive thread offset within block
  if (t == 255) partials[b] = sh[255];
  if (base+0 < n) rp[base+0] = ex;
  if (base+1 < n) rp[base+1] = ex + v0;
  if (base+2 < n) rp[base+2] = ex + v0 + v1;
  if (base+3 < n) rp[base+3] = ex + v0 + v1 + v2;
}

__global__ void k_scan2(int* __restrict__ partials, int nb) {
  __shared__ int sh[256];
  int t = threadIdx.x;
  int v = (t < nb) ? partials[t] : 0;
  sh[t] = v;
  __syncthreads();
  for (int off = 1; off < 256; off <<= 1) {
    int val = (t >= off) ? sh[t - off] : 0;
    __syncthreads();
    sh[t] += val;
    __syncthreads();
  }
  if (t < nb) partials[t] = sh[t] - v;   // exclusive block offsets
}

__global__ void k_scan3(int* __restrict__ rp, const int* __restrict__ partials,
                        const int* __restrict__ deg, float* __restrict__ norm,
                        int n, int E) {
  int i = blockIdx.x*blockDim.x + threadIdx.x;
  if (i == 0) rp[n] = E;
  if (i >= n) return;
  rp[i] += partials[i >> 10];
  norm[i] = rsqrtf(1.0f + (float)deg[i]);
}

// ---------------- scatter cols into CSR ----------------
__global__ void k_scatter(const int* __restrict__ row, const int* __restrict__ col,
                          const int* __restrict__ rp, int* __restrict__ cnt,
                          int* __restrict__ colbuf, int E) {
  int i = blockIdx.x*blockDim.x + threadIdx.x;
  int stride = gridDim.x*blockDim.x;
  for (; i < E; i += stride) {
    int r = row[i];
    int p = rp[r] + atomicAdd(&cnt[r], 1);
    colbuf[p] = col[i];
  }
}

// ---------------- xemb tiled GEMM: hbf = bf16( norm * ([x|pe] @ W + b) ) ----------------
__global__ __launch_bounds__(256) void k_xemb(
    const float* __restrict__ x, const float* __restrict__ pe,
    const float* __restrict__ W, const float* __restrict__ bvec,
    const float* __restrict__ norm, unsigned short* __restrict__ hbf, int n) {
  __shared__ float As[8][64];    // [k][m]
  __shared__ float Bs[8][64];    // [k][n]
  int t  = threadIdx.x;
  int i0 = blockIdx.x*64;
  int n0 = blockIdx.y*64;
  int am = t >> 2;
  int ak = (t & 3) * 2;
  int arow = i0 + am; if (arow >= n) arow = n - 1;
  int bk = t >> 5;
  int bn = (t & 31) * 2;
  int tx = t & 15, ty = t >> 4;
  float acc[4][4] = {};
  for (int k0 = 0; k0 < 264; k0 += 8) {
    float2 av;
    if (k0 < 256) av = *(const float2*)&x[(size_t)arow*IN + k0 + ak];
    else          av = *(const float2*)&pe[(size_t)arow*NLOC + ak];
    float2 bv = *(const float2*)&W[(size_t)(k0 + bk)*H + n0 + bn];
    __syncthreads();
    As[ak][am] = av.x; As[ak+1][am] = av.y;
    Bs[bk][bn] = bv.x; Bs[bk][bn+1] = bv.y;
    __syncthreads();
    #pragma unroll
    for (int k = 0; k < 8; ++k) {
      float4 a = *(const float4*)&As[k][ty*4];
      float4 b = *(const float4*)&Bs[k][tx*4];
      float aa[4] = {a.x,a.y,a.z,a.w};
      float bb[4] = {b.x,b.y,b.z,b.w};
      #pragma unroll
      for (int ii = 0; ii < 4; ++ii)
        #pragma unroll
        for (int jj = 0; jj < 4; ++jj) acc[ii][jj] += aa[ii]*bb[jj];
    }
  }
  float4 bias = *(const float4*)&bvec[n0 + tx*4];
  float bb4[4] = {bias.x, bias.y, bias.z, bias.w};
  #pragma unroll
  for (int ii = 0; ii < 4; ++ii) {
    int i = i0 + ty*4 + ii;
    if (i < n) {
      float nr = norm[i];
      unsigned short s0 = f2bf(nr*(acc[ii][0] + bb4[0]));
      unsigned short s1 = f2bf(nr*(acc[ii][1] + bb4[1]));
      unsigned short s2 = f2bf(nr*(acc[ii][2] + bb4[2]));
      unsigned short s3 = f2bf(nr*(acc[ii][3] + bb4[3]));
      uint2 pk;
      pk.x = (unsigned)s0 | ((unsigned)s1 << 16);
      pk.y = (unsigned)s2 | ((unsigned)s3 << 16);
      *(uint2*)&hbf[(size_t)i*H + n0 + tx*4] = pk;
    }
  }
}

// ---------------- layer: u = norm*(A@hs + hs); out (+)= jk*u; hbf_next = bf16(norm*u) ----------------
__global__ __launch_bounds__(256) void k_layer(
    const unsigned short* __restrict__ hbf, const int* __restrict__ rp,
    const int* __restrict__ colbuf, const float* __restrict__ norm,
    const float* __restrict__ jkp, int l, int first, int last,
    float* __restrict__ out, unsigned short* __restrict__ hbf_next, int n) {
  int wid = (int)(((size_t)blockIdx.x*blockDim.x + threadIdx.x) >> 6);
  if (wid >= n) return;
  int lane = threadIdx.x & 63;
  const uint2* gb = (const uint2*)hbf + lane;   // row stride = 64 uint2
  int start = rp[wid], end = rp[wid+1];
  float4 acc = make_float4(0.f,0.f,0.f,0.f);
  int j = start;
  for (; j + 8 <= end; j += 8) {
    int c0 = colbuf[j],   c1 = colbuf[j+1], c2 = colbuf[j+2], c3 = colbuf[j+3];
    int c4 = colbuf[j+4], c5 = colbuf[j+5], c6 = colbuf[j+6], c7 = colbuf[j+7];
    uint2 v0 = gb[(size_t)c0*64];
    uint2 v1 = gb[(size_t)c1*64];
    uint2 v2 = gb[(size_t)c2*64];
    uint2 v3 = gb[(size_t)c3*64];
    uint2 v4 = gb[(size_t)c4*64];
    uint2 v5 = gb[(size_t)c5*64];
    uint2 v6 = gb[(size_t)c6*64];
    uint2 v7 = gb[(size_t)c7*64];
    acc.x += ((bflo(v0.x)+bflo(v1.x)) + (bflo(v2.x)+bflo(v3.x)))
           + ((bflo(v4.x)+bflo(v5.x)) + (bflo(v6.x)+bflo(v7.x)));
    acc.y += ((bfhi(v0.x)+bfhi(v1.x)) + (bfhi(v2.x)+bfhi(v3.x)))
           + ((bfhi(v4.x)+bfhi(v5.x)) + (bfhi(v6.x)+bfhi(v7.x)));
    acc.z += ((bflo(v0.y)+bflo(v1.y)) + (bflo(v2.y)+bflo(v3.y)))
           + ((bflo(v4.y)+bflo(v5.y)) + (bflo(v6.y)+bflo(v7.y)));
    acc.w += ((bfhi(v0.y)+bfhi(v1.y)) + (bfhi(v2.y)+bfhi(v3.y)))
           + ((bfhi(v4.y)+bfhi(v5.y)) + (bfhi(v6.y)+bfhi(v7.y)));
  }
  for (; j + 2 <= end; j += 2) {
    int c0 = colbuf[j], c1 = colbuf[j+1];
    uint2 v0 = gb[(size_t)c0*64];
    uint2 v1 = gb[(size_t)c1*64];
    acc.x += bflo(v0.x)+bflo(v1.x); acc.y += bfhi(v0.x)+bfhi(v1.x);
    acc.z += bflo(v0.y)+bflo(v1.y); acc.w += bfhi(v0.y)+bfhi(v1.y);
  }
  if (j < end) {
    int c0 = colbuf[j];
    uint2 v0 = gb[(size_t)c0*64];
    acc.x += bflo(v0.x); acc.y += bfhi(v0.x);
    acc.z += bflo(v0.y); acc.w += bfhi(v0.y);
  }
  // self term
  uint2 sv = gb[(size_t)wid*64];
  acc.x += bflo(sv.x); acc.y += bfhi(sv.x);
  acc.z += bflo(sv.y); acc.w += bfhi(sv.y);
  float nr = norm[wid];
  float jk = jkp[l];
  float4 u = make_float4(nr*acc.x, nr*acc.y, nr*acc.z, nr*acc.w);
  float* op = out + (size_t)wid*H + lane*4;
  if (first) {
    *(float4*)op = make_float4(jk*u.x, jk*u.y, jk*u.z, jk*u.w);
  } else {
    float4 o = *(const float4*)op;
    o.x += jk*u.x; o.y += jk*u.y; o.z += jk*u.z; o.w += jk*u.w;
    *(float4*)op = o;
  }
  if (!last) {
    unsigned short s0 = f2bf(nr*u.x);
    unsigned short s1 = f2bf(nr*u.y);
    unsigned short s2 = f2bf(nr*u.z);
    unsigned short s3 = f2bf(nr*u.w);
    uint2 pk;
    pk.x = (unsigned)s0 | ((unsigned)s1 << 16);
    pk.y = (unsigned)s2 | ((unsigned)s3 << 16);
    *(uint2*)&hbf_next[(size_t)wid*H + lane*4] = pk;
  }
}

extern "C" void kernel_launch(void* const* d_in, const int* in_sizes, int n_in,
                              void* d_out, int out_size, void* d_ws, size_t ws_size,
                              hipStream_t stream) {
  const float* x       = (const float*)d_in[0];
  const float* pos_emb = (const float*)d_in[1];
  const float* lap_pe  = (const float*)d_in[2];
  const float* W_pos   = (const float*)d_in[3];
  const float* b_pos   = (const float*)d_in[4];
  const float* W_xemb  = (const float*)d_in[5];
  const float* b_xemb  = (const float*)d_in[6];
  const float* jkp     = (const float*)d_in[7];
  const int*   row     = (const int*)d_in[8];
  const int*   col     = (const int*)d_in[9];
  int N = in_sizes[0] / IN;
  int E = in_sizes[8];
  float* out = (float*)d_out;

  char* p = (char*)d_ws;
  auto alloc = [&](size_t bytes) {
    char* r = p; p += (bytes + 255) & ~(size_t)255; return r;
  };
  unsigned short* bfA = (unsigned short*)alloc((size_t)N*H*2);
  unsigned short* bfB = (unsigned short*)alloc((size_t)N*H*2);
  int*   colbuf = (int*)  alloc((size_t)E*4);
  float* pe     = (float*)alloc((size_t)N*NLOC*4);
  int*   deg    = (int*)  alloc((size_t)N*4);
  int*   cnt    = (int*)  alloc((size_t)N*4);
  int*   rp     = (int*)  alloc((size_t)(N+1)*4);
  int*   partials=(int*)  alloc(256*4);
  float* norm   = (float*)alloc((size_t)N*4);

  hipMemsetAsync(deg, 0, (size_t)N*4, stream);
  hipMemsetAsync(cnt, 0, (size_t)N*4, stream);

  k_deg<<<2048, 256, 0, stream>>>(row, deg, E);
  k_pe<<<(N+255)/256, 256, 0, stream>>>(pos_emb, lap_pe, W_pos, b_pos, pe, N);
  int nb = (N + 1023)/1024;                       // 98 (<=256)
  k_scan1<<<nb, 256, 0, stream>>>(deg, rp, partials, N);
  k_scan2<<<1, 256, 0, stream>>>(partials, nb);
  k_scan3<<<(N+255)/256, 256, 0, stream>>>(rp, partials, deg, norm, N, E);
  k_scatter<<<2048, 256, 0, stream>>>(row, col, rp, cnt, colbuf, E);

  dim3 gg((N+63)/64, 4);
  k_xemb<<<gg, 256, 0, stream>>>(x, pe, W_xemb, b_xemb, norm, bfA, N);

  int lg = (int)(((size_t)N*64 + 255)/256);   // one wave per row
  k_layer<<<lg, 256, 0, stream>>>(bfA, rp, colbuf, norm, jkp, 0, 1, 0, out, bfB, N);
  k_layer<<<lg, 256, 0, stream>>>(bfB, rp, colbuf, norm, jkp, 1, 0, 0, out, bfA, N);
  k_layer<<<lg, 256, 0, stream>>>(bfA, rp, colbuf, norm, jkp, 2, 0, 1, out, bfB, N);
}